// Round 7
// baseline (206.841 us; speedup 1.0000x reference)
//
#include <hip/hip_runtime.h>

// GCN 2-layer. CSR by dst (counting sort) per call.
// R7: normalization factored out of the edge loop. GEMM epilogues write
// g = dinv[row] * (row @ W) in fp16; aggregation is a pure gather-sum of g
// rows; epilogue multiplies by dinv[dst] once (+bias, +relu). No per-edge
// weights -> meta is just src (4B), fill has no random dinv gathers.

#define N_NODES 20000
#define N_EDGES 640000
#define IN_DIM 128
#define HID_DIM 128
#define OUT_DIM 64

#define SCAN_NB ((N_NODES + 255) / 256)  // 79
#define DEG_NB ((N_EDGES + 255) / 256)   // 2500
#define WT_NB ((128 * 128 + 64 * 128 + 255) / 256)  // 96

typedef _Float16 half8_t __attribute__((ext_vector_type(8)));
typedef float float4_t __attribute__((ext_vector_type(4)));

// Fused: blocks [0, DEG_NB) histogram dst; blocks [DEG_NB, ...) transpose+cast
// W1/W2 to fp16 WT[col][k].
__global__ void k_degwt(const int* __restrict__ dst, int* __restrict__ deg,
                        const float* __restrict__ W1, const float* __restrict__ W2,
                        _Float16* __restrict__ WT1, _Float16* __restrict__ WT2) {
    int b = blockIdx.x;
    if (b < DEG_NB) {
        int e = b * 256 + threadIdx.x;
        if (e < N_EDGES) atomicAdd(&deg[dst[e]], 1);
    } else {
        int i = (b - DEG_NB) * 256 + threadIdx.x;
        if (i < 128 * 128) {
            int c = i >> 7, k = i & 127;
            WT1[i] = (_Float16)W1[k * 128 + c];
        } else {
            int o = i - 128 * 128;
            if (o < 64 * 128) {
                int c = o >> 7, k = o & 127;
                WT2[o] = (_Float16)W2[k * 64 + c];
            }
        }
    }
}

// One-kernel scan: block b sums cnt[0, 256b) for its global offset (L2-hot),
// then intra-block exclusive scan -> rowptr/cursor/dinv.
__global__ __launch_bounds__(256) void k_scan(const int* __restrict__ cnt,
                                              int* __restrict__ rowptr,
                                              int* __restrict__ cursor,
                                              float* __restrict__ dinv) {
    const int b = blockIdx.x, t = threadIdx.x;
    const int lane = t & 63, wv = t >> 6;
    __shared__ int ws[4], ps[4];

    int pre = 0;
    for (int i = t; i < b * 256; i += 256) pre += cnt[i];
    for (int off = 32; off > 0; off >>= 1) pre += __shfl_down(pre, off, 64);
    if (lane == 0) ps[wv] = pre;

    int i = b * 256 + t;
    int c = (i < N_NODES) ? cnt[i] : 0;
    int v = c;
    for (int off = 1; off < 64; off <<= 1) {
        int u = __shfl_up(v, off, 64);
        if (lane >= off) v += u;
    }
    if (lane == 63) ws[wv] = v;
    __syncthreads();

    int block_pre = ps[0] + ps[1] + ps[2] + ps[3];
    int wadd = 0;
    for (int k = 0; k < 4; ++k)
        if (k < wv) wadd += ws[k];
    int excl = block_pre + wadd + (v - c);
    if (i < N_NODES) {
        rowptr[i] = excl;
        cursor[i] = excl;
        dinv[i] = rsqrtf((float)c + 1.0f);
    }
    if (b == SCAN_NB - 1 && t == 0) rowptr[N_NODES] = N_EDGES;
}

// esrc[pos] = src. cursor pre-seeded with rowptr. No weights (R7).
__global__ void k_fill(const int* __restrict__ src, const int* __restrict__ dst,
                       int* __restrict__ cursor, int* __restrict__ esrc) {
    int e = blockIdx.x * blockDim.x + threadIdx.x;
    if (e >= N_EDGES) return;
    int s = src[e], d = dst[e];
    int pos = atomicAdd(&cursor[d], 1);
    esrc[pos] = s;
}

// GEMM1: g1 = dinv * (x @ W1), MFMA f16, A fp32->cvt, out fp16.
// One wave per (16-row strip, 64-col half): 2500 wave-tasks (R7: was 1250,
// ~1.2 waves/SIMD -> poor latency hiding).
__global__ __launch_bounds__(256) void k_mgemm1(const float* __restrict__ A,
                                                const _Float16* __restrict__ WT,
                                                const float* __restrict__ dinv,
                                                _Float16* __restrict__ G) {
    const int wave = threadIdx.x >> 6;
    const int lane = threadIdx.x & 63;
    const int task = blockIdx.x * 4 + wave;
    if (task >= 2 * (N_NODES / 16)) return;
    const int strip = task >> 1;
    const int nh = task & 1;         // which 64-col half
    const int row0 = strip * 16;
    const int mrow = row0 + (lane & 15);
    const int kq = (lane >> 4) * 8;

    half8_t af[4];
#pragma unroll
    for (int kc = 0; kc < 4; ++kc) {
        const float* ap = A + (size_t)mrow * 128 + kc * 32 + kq;
        float4_t f0 = *(const float4_t*)ap;
        float4_t f1 = *(const float4_t*)(ap + 4);
        half8_t h;
        h[0] = (_Float16)f0[0]; h[1] = (_Float16)f0[1];
        h[2] = (_Float16)f0[2]; h[3] = (_Float16)f0[3];
        h[4] = (_Float16)f1[0]; h[5] = (_Float16)f1[1];
        h[6] = (_Float16)f1[2]; h[7] = (_Float16)f1[3];
        af[kc] = h;
    }

    float4_t acc[4];
#pragma unroll
    for (int nt = 0; nt < 4; ++nt) acc[nt] = (float4_t)(0.0f);

#pragma unroll
    for (int nt = 0; nt < 4; ++nt) {
        const _Float16* wp = WT + (size_t)((nh * 4 + nt) * 16 + (lane & 15)) * 128 + kq;
#pragma unroll
        for (int kc = 0; kc < 4; ++kc) {
            half8_t bf = *(const half8_t*)(wp + kc * 32);
            acc[nt] = __builtin_amdgcn_mfma_f32_16x16x32_f16(af[kc], bf, acc[nt], 0, 0, 0);
        }
    }

#pragma unroll
    for (int r = 0; r < 4; ++r) {
        int row = row0 + (lane >> 4) * 4 + r;
        float dv = dinv[row];
#pragma unroll
        for (int nt = 0; nt < 4; ++nt)
            G[(size_t)row * 128 + (nh * 4 + nt) * 16 + (lane & 15)] =
                (_Float16)(dv * acc[nt][r]);
    }
}

// GEMM2: g2 = dinv * (h1p @ W2), A fp16 direct, out fp16. 2500 wave-tasks.
__global__ __launch_bounds__(256) void k_mgemm2(const _Float16* __restrict__ A,
                                                const _Float16* __restrict__ WT,
                                                const float* __restrict__ dinv,
                                                _Float16* __restrict__ G) {
    const int wave = threadIdx.x >> 6;
    const int lane = threadIdx.x & 63;
    const int task = blockIdx.x * 4 + wave;
    if (task >= 2 * (N_NODES / 16)) return;
    const int strip = task >> 1;
    const int nh = task & 1;         // which 32-col half
    const int row0 = strip * 16;
    const int mrow = row0 + (lane & 15);
    const int kq = (lane >> 4) * 8;

    half8_t af[4];
#pragma unroll
    for (int kc = 0; kc < 4; ++kc)
        af[kc] = *(const half8_t*)(A + (size_t)mrow * 128 + kc * 32 + kq);

    float4_t acc[2];
#pragma unroll
    for (int nt = 0; nt < 2; ++nt) acc[nt] = (float4_t)(0.0f);

#pragma unroll
    for (int nt = 0; nt < 2; ++nt) {
        const _Float16* wp = WT + (size_t)((nh * 2 + nt) * 16 + (lane & 15)) * 128 + kq;
#pragma unroll
        for (int kc = 0; kc < 4; ++kc) {
            half8_t bf = *(const half8_t*)(wp + kc * 32);
            acc[nt] = __builtin_amdgcn_mfma_f32_16x16x32_f16(af[kc], bf, acc[nt], 0, 0, 0);
        }
    }

#pragma unroll
    for (int r = 0; r < 4; ++r) {
        int row = row0 + (lane >> 4) * 4 + r;
        float dv = dinv[row];
#pragma unroll
        for (int nt = 0; nt < 2; ++nt)
            G[(size_t)row * 64 + (nh * 2 + nt) * 16 + (lane & 15)] =
                (_Float16)(dv * acc[nt][r]);
    }
}

// F=128 agg: one wave/node, 4 edges/iter (16 lanes x half8 per row), pure
// gather-sum of g rows; epilogue: *dinv[node], +bias, relu, fp16 out.
__global__ __launch_bounds__(256) void k_agg128(const int* __restrict__ rowptr,
                                                const int* __restrict__ esrc,
                                                const _Float16* __restrict__ g,
                                                const float* __restrict__ dinv,
                                                const float* __restrict__ bias,
                                                _Float16* __restrict__ out) {
    const int wave = threadIdx.x >> 6;
    const int lane = threadIdx.x & 63;
    const int node = blockIdx.x * 4 + wave;
    if (node >= N_NODES) return;
    const int eidx = lane >> 4;
    const int flane = lane & 15;

    const int beg = rowptr[node], end = rowptr[node + 1];

    float acc[8];
#pragma unroll
    for (int p = 0; p < 8; ++p) acc[p] = 0.0f;
    if (lane < 16) {   // self-loop: + g[node]
        half8_t s = *(const half8_t*)(g + (size_t)node * 128 + flane * 8);
#pragma unroll
        for (int p = 0; p < 8; ++p) acc[p] = (float)s[p];
    }

    int j = beg;
    for (; j + 3 < end; j += 4) {
        int s = esrc[j + eidx];
        half8_t r = *(const half8_t*)(g + (size_t)s * 128 + flane * 8);
#pragma unroll
        for (int p = 0; p < 8; ++p) acc[p] += (float)r[p];
    }
    if (j < end) {
        int idx = j + eidx;
        int s = esrc[(idx < end) ? idx : (end - 1)];
        float valid = (idx < end) ? 1.0f : 0.0f;
        half8_t r = *(const half8_t*)(g + (size_t)s * 128 + flane * 8);
#pragma unroll
        for (int p = 0; p < 8; ++p) acc[p] += valid * (float)r[p];
    }

#pragma unroll
    for (int p = 0; p < 8; ++p) {
        acc[p] += __shfl_xor(acc[p], 32, 64);
        acc[p] += __shfl_xor(acc[p], 16, 64);
    }

    if (lane < 16) {
        float dv = dinv[node];
        float4_t b0 = *(const float4_t*)(bias + flane * 8);
        float4_t b1 = *(const float4_t*)(bias + flane * 8 + 4);
        half8_t o;
        o[0] = (_Float16)fmaxf(acc[0] * dv + b0[0], 0.0f);
        o[1] = (_Float16)fmaxf(acc[1] * dv + b0[1], 0.0f);
        o[2] = (_Float16)fmaxf(acc[2] * dv + b0[2], 0.0f);
        o[3] = (_Float16)fmaxf(acc[3] * dv + b0[3], 0.0f);
        o[4] = (_Float16)fmaxf(acc[4] * dv + b1[0], 0.0f);
        o[5] = (_Float16)fmaxf(acc[5] * dv + b1[1], 0.0f);
        o[6] = (_Float16)fmaxf(acc[6] * dv + b1[2], 0.0f);
        o[7] = (_Float16)fmaxf(acc[7] * dv + b1[3], 0.0f);
        *(half8_t*)(out + (size_t)node * 128 + flane * 8) = o;
    }
}

// F=64 agg: one wave/node, 8 edges/iter (8 lanes x half8 per row).
// Epilogue: *dinv[node], +bias, fp32 out.
__global__ __launch_bounds__(256) void k_agg64(const int* __restrict__ rowptr,
                                               const int* __restrict__ esrc,
                                               const _Float16* __restrict__ g,
                                               const float* __restrict__ dinv,
                                               const float* __restrict__ bias,
                                               float* __restrict__ out) {
    const int wave = threadIdx.x >> 6;
    const int lane = threadIdx.x & 63;
    const int node = blockIdx.x * 4 + wave;
    if (node >= N_NODES) return;
    const int eidx = lane >> 3;
    const int flane = lane & 7;

    const int beg = rowptr[node], end = rowptr[node + 1];

    float acc[8];
#pragma unroll
    for (int p = 0; p < 8; ++p) acc[p] = 0.0f;
    if (lane < 8) {
        half8_t s = *(const half8_t*)(g + (size_t)node * 64 + flane * 8);
#pragma unroll
        for (int p = 0; p < 8; ++p) acc[p] = (float)s[p];
    }

    int j = beg;
    for (; j + 7 < end; j += 8) {
        int s = esrc[j + eidx];
        half8_t r = *(const half8_t*)(g + (size_t)s * 64 + flane * 8);
#pragma unroll
        for (int p = 0; p < 8; ++p) acc[p] += (float)r[p];
    }
    if (j < end) {
        int idx = j + eidx;
        int s = esrc[(idx < end) ? idx : (end - 1)];
        float valid = (idx < end) ? 1.0f : 0.0f;
        half8_t r = *(const half8_t*)(g + (size_t)s * 64 + flane * 8);
#pragma unroll
        for (int p = 0; p < 8; ++p) acc[p] += valid * (float)r[p];
    }

#pragma unroll
    for (int p = 0; p < 8; ++p) {
        acc[p] += __shfl_xor(acc[p], 32, 64);
        acc[p] += __shfl_xor(acc[p], 16, 64);
        acc[p] += __shfl_xor(acc[p], 8, 64);
    }

    if (lane < 8) {
        float dv = dinv[node];
        float4_t b0 = *(const float4_t*)(bias + flane * 8);
        float4_t b1 = *(const float4_t*)(bias + flane * 8 + 4);
        float4_t o0, o1;
        o0[0] = acc[0] * dv + b0[0]; o0[1] = acc[1] * dv + b0[1];
        o0[2] = acc[2] * dv + b0[2]; o0[3] = acc[3] * dv + b0[3];
        o1[0] = acc[4] * dv + b1[0]; o1[1] = acc[5] * dv + b1[1];
        o1[2] = acc[6] * dv + b1[2]; o1[3] = acc[7] * dv + b1[3];
        *(float4_t*)(out + (size_t)node * 64 + flane * 8) = o0;
        *(float4_t*)(out + (size_t)node * 64 + flane * 8 + 4) = o1;
    }
}

extern "C" void kernel_launch(void* const* d_in, const int* in_sizes, int n_in,
                              void* d_out, int out_size, void* d_ws, size_t ws_size,
                              hipStream_t stream) {
    const float* x  = (const float*)d_in[0];
    const int*   ei = (const int*)d_in[1];
    const float* W1 = (const float*)d_in[2];
    const float* b1 = (const float*)d_in[3];
    const float* W2 = (const float*)d_in[4];
    const float* b2 = (const float*)d_in[5];

    const int* src = ei;
    const int* dst = ei + N_EDGES;

    char* w = (char*)d_ws;
    int*       esrc   = (int*)w;       w += sizeof(int) * N_EDGES;
    _Float16*  g1     = (_Float16*)w;  w += sizeof(_Float16) * (size_t)N_NODES * HID_DIM;
    _Float16*  h1p    = (_Float16*)w;  w += sizeof(_Float16) * (size_t)N_NODES * HID_DIM;
    _Float16*  g2     = (_Float16*)w;  w += sizeof(_Float16) * (size_t)N_NODES * OUT_DIM;
    _Float16*  WT1    = (_Float16*)w;  w += sizeof(_Float16) * 128 * 128;
    _Float16*  WT2    = (_Float16*)w;  w += sizeof(_Float16) * 64 * 128;
    int*       deg    = (int*)w;       w += sizeof(int) * N_NODES;
    int*       rowptr = (int*)w;       w += sizeof(int) * (N_NODES + 2);
    int*       cursor = (int*)w;       w += sizeof(int) * N_NODES;
    float*     dinv   = (float*)w;     w += sizeof(float) * N_NODES;
    float*     out    = (float*)d_out;

    hipMemsetAsync(deg, 0, sizeof(int) * N_NODES, stream);

    // CSR build + weight transpose
    k_degwt<<<DEG_NB + WT_NB, 256, 0, stream>>>(dst, deg, W1, W2, WT1, WT2);
    k_scan<<<SCAN_NB, 256, 0, stream>>>(deg, rowptr, cursor, dinv);
    k_fill<<<(N_EDGES + 255) / 256, 256, 0, stream>>>(src, dst, cursor, esrc);

    // Layer 1
    k_mgemm1<<<(2 * (N_NODES / 16) + 3) / 4, 256, 0, stream>>>(x, WT1, dinv, g1);
    k_agg128<<<(N_NODES + 3) / 4, 256, 0, stream>>>(rowptr, esrc, g1, dinv, b1, h1p);

    // Layer 2
    k_mgemm2<<<(2 * (N_NODES / 16) + 3) / 4, 256, 0, stream>>>(h1p, WT2, dinv, g2);
    k_agg64<<<(N_NODES + 3) / 4, 256, 0, stream>>>(rowptr, esrc, g2, dinv, b2, out);
}